// Round 9
// baseline (180.553 us; speedup 1.0000x reference)
//
#include <hip/hip_runtime.h>
#include <cstdint>

typedef _Float16 half2_t __attribute__((ext_vector_type(2)));
typedef _Float16 half4_t __attribute__((ext_vector_type(4)));
typedef _Float16 half8_t __attribute__((ext_vector_type(8)));
typedef float floatx4 __attribute__((ext_vector_type(4)));

#define T_SEQ 4096
#define D_HEAD 128
#define SCALE_LOG2 0.12751742526f  // log2(e)/sqrt(128), folded into q at proj time

__device__ __forceinline__ void gload16(const void* src, void* dst_lds) {
    using gptr_t = const __attribute__((address_space(1))) unsigned int*;
    using lptr_t = __attribute__((address_space(3))) unsigned int*;
    __builtin_amdgcn_global_load_lds((gptr_t)(uintptr_t)src,
                                     (lptr_t)(unsigned int)(uintptr_t)dst_lds, 16, 0, 0);
}

__device__ __forceinline__ float exp2_raw(float x) {
#if __has_builtin(__builtin_amdgcn_exp2f)
    return __builtin_amdgcn_exp2f(x);   // raw v_exp_f32
#else
    return exp2f(x);
#endif
}

// ---------------- QKV projection (MFMA f16, fp32 accumulate) ----------------
__global__ __launch_bounds__(256) void proj_kernel(
    const float* __restrict__ x,
    const float* __restrict__ Wq, const float* __restrict__ bq,
    const float* __restrict__ Wk, const float* __restrict__ bk,
    const float* __restrict__ Wv, const float* __restrict__ bv,
    _Float16* __restrict__ qf, _Float16* __restrict__ kf, _Float16* __restrict__ vt)
{
    __shared__ __align__(16) _Float16 Ws[128 * 136];
    __shared__ __align__(16) _Float16 xs[64 * 136];

    const int t = threadIdx.x;
    const int mat = blockIdx.y;
    const float* W = (mat == 0) ? Wq : (mat == 1) ? Wk : Wv;
    const float* bias = (mat == 0) ? bq : (mat == 1) ? bk : bv;
    const float osc = (mat == 0) ? SCALE_LOG2 : 1.0f;
    const int r0 = blockIdx.x * 64;

    {
        const int o = t >> 1;
        const int i0 = (t & 1) * 64;
        for (int jj = 0; jj < 8; ++jj) {
            floatx4 w0 = *reinterpret_cast<const floatx4*>(W + o * 128 + i0 + jj * 8);
            floatx4 w1 = *reinterpret_cast<const floatx4*>(W + o * 128 + i0 + jj * 8 + 4);
            half8_t h;
            h[0]=(_Float16)w0[0]; h[1]=(_Float16)w0[1]; h[2]=(_Float16)w0[2]; h[3]=(_Float16)w0[3];
            h[4]=(_Float16)w1[0]; h[5]=(_Float16)w1[1]; h[6]=(_Float16)w1[2]; h[7]=(_Float16)w1[3];
            *reinterpret_cast<half8_t*>(&Ws[o * 136 + i0 + jj * 8]) = h;
        }
    }
    {
        const int row = t >> 2;
        const int c0 = (t & 3) * 32;
        for (int jj = 0; jj < 4; ++jj) {
            floatx4 w0 = *reinterpret_cast<const floatx4*>(x + (size_t)(r0 + row) * 128 + c0 + jj * 8);
            floatx4 w1 = *reinterpret_cast<const floatx4*>(x + (size_t)(r0 + row) * 128 + c0 + jj * 8 + 4);
            half8_t h;
            h[0]=(_Float16)w0[0]; h[1]=(_Float16)w0[1]; h[2]=(_Float16)w0[2]; h[3]=(_Float16)w0[3];
            h[4]=(_Float16)w1[0]; h[5]=(_Float16)w1[1]; h[6]=(_Float16)w1[2]; h[7]=(_Float16)w1[3];
            *reinterpret_cast<half8_t*>(&xs[row * 136 + c0 + jj * 8]) = h;
        }
    }
    __syncthreads();

    const int w = t >> 6;
    const int lane = t & 63;
    const int lo = lane & 15, hi = lane >> 4;

    floatx4 acc[8] = {};
    for (int dc = 0; dc < 4; ++dc) {
        half8_t a8 = *reinterpret_cast<const half8_t*>(&xs[(w * 16 + lo) * 136 + dc * 32 + hi * 8]);
        for (int ot = 0; ot < 8; ++ot) {
            half8_t b8 = *reinterpret_cast<const half8_t*>(&Ws[(ot * 16 + lo) * 136 + dc * 32 + hi * 8]);
            acc[ot] = __builtin_amdgcn_mfma_f32_16x16x32_f16(a8, b8, acc[ot], 0, 0, 0);
        }
    }
    __syncthreads();

    float bb[8];
    for (int ot = 0; ot < 8; ++ot) bb[ot] = bias[ot * 16 + lo];

    if (mat < 2) {
        _Float16* ol = xs;
        for (int ot = 0; ot < 8; ++ot)
            for (int r = 0; r < 4; ++r)
                ol[(w * 16 + hi * 4 + r) * 136 + ot * 16 + lo] = (_Float16)((acc[ot][r] + bb[ot]) * osc);
        __syncthreads();
        _Float16* dst = (mat == 0) ? qf : kf;
        for (int i = 0; i < 4; ++i) {
            int c = t + 256 * i;
            int row = c >> 4, p = c & 15;
            half8_t v = *reinterpret_cast<const half8_t*>(&ol[row * 136 + p * 8]);
            *reinterpret_cast<half8_t*>(dst + (size_t)(r0 + row) * 128 + p * 8) = v;
        }
    } else {
        _Float16* vl = Ws;  // [128][72]
        for (int ot = 0; ot < 8; ++ot)
            for (int r = 0; r < 4; ++r)
                vl[(ot * 16 + lo) * 72 + w * 16 + hi * 4 + r] = (_Float16)(acc[ot][r] + bb[ot]);
        __syncthreads();
        const int b = r0 >> 12, tl0 = r0 & 4095;
        for (int i = 0; i < 4; ++i) {
            int c = t + 256 * i;
            int d = c >> 3, p = c & 7;
            half8_t v = *reinterpret_cast<const half8_t*>(&vl[d * 72 + p * 8]);
            *reinterpret_cast<half8_t*>(vt + ((size_t)(b * 128 + d)) * 4096 + tl0 + p * 8) = v;
        }
    }
}

// ---------------- flash attention ----------------
// 256 blocks x 512 threads = 8 waves: 2 q-groups (32 q as 2x16) x 4 kv-splits (16 kv).
// kv tile = 64. K double-buffered in LDS (2 x 16KB, global_load_lds + swizzle, exactly
// round-7 mechanics). V bypasses LDS entirely: L2 -> registers, double-buffered one
// tile ahead (2 reg sets). One barrier per tile. Round-7 TILE order preserved.
__global__ __launch_bounds__(512, 1) void attn_kernel(
    const _Float16* __restrict__ qf, const _Float16* __restrict__ kf,
    const _Float16* __restrict__ vt, float* __restrict__ out)
{
    __shared__ __align__(16) char smem[36864];   // 2x16KB K buffers | merge area

    const int tid = threadIdx.x;
    const int w = tid >> 6, lane = tid & 63;
    const int lo = lane & 15, hi = lane >> 4;
    const int qg = w & 1, ksp = w >> 1;

    // XCD-aware swizzle: 32 consecutive wg per XCD -> one batch's K/V in that XCD's L2
    const int bx = blockIdx.x;
    const int wg = (bx & 7) * 32 + (bx >> 3);
    const int b = wg >> 6;
    const int q0 = (wg & 63) * 64;

    const char* kbc = (const char*)(kf + (size_t)b * T_SEQ * 128);
    const char* vbc = (const char*)(vt + (size_t)b * 128 * T_SEQ);

    // K staging (round-7): 2 gload16/thread. LDS[row][slot] = K[row][slot ^ (row&7)].
    int koff[2], kdst[2];
#pragma unroll
    for (int r = 0; r < 2; ++r) {
        int seg = w * 2 + r;
        int slot = lane & 15;
        int row = seg * 4 + (lane >> 4);
        koff[r] = row * 256 + ((slot ^ (row & 7)) << 4);
        kdst[r] = seg * 1024 + lane * 16;
    }
    // K LDS read offsets (loop-invariant)
    int kro[4];
#pragma unroll
    for (int dc = 0; dc < 4; ++dc)
        kro[dc] = (ksp * 16 + lo) * 256 + (((dc * 4 + hi) ^ (lo & 7)) << 4);

    // V direct-from-L2 offset: row d = dt*16 + lo (8192B stride), kv = ksp*16 + hi*4
    const int vgo = lo * 8192 + ksp * 32 + hi * 8;

    // Q fragments (pre-scaled by log2(e)/sqrt(D)): d-enum dc*32+hi*8+j, matches K-side
    half8_t qfA[4], qfB[4];
    {
        const _Float16* qa = qf + ((size_t)b * T_SEQ + q0 + qg * 32 + lo) * 128;
        const _Float16* qb = qa + 16 * 128;
#pragma unroll
        for (int dc = 0; dc < 4; ++dc) {
            qfA[dc] = *reinterpret_cast<const half8_t*>(qa + dc * 32 + hi * 8);
            qfB[dc] = *reinterpret_cast<const half8_t*>(qb + dc * 32 + hi * 8);
        }
    }

    floatx4 accA[8] = {}, accB[8] = {};
    float mA = -1e30f, mB = -1e30f, lA = 0.f, lB = 0.f;   // l is LANE-PARTIAL
    half4_t paA = {}, paB = {};                           // P of previous tile
    half4_t v0[8], v1[8];                                 // V reg sets (tile parity)

    // prologue: K(0) -> buf0, V(0) -> v0
    gload16(kbc + koff[0], smem + kdst[0]);
    gload16(kbc + koff[1], smem + kdst[1]);
#pragma unroll
    for (int dt = 0; dt < 8; ++dt)
        v0[dt] = *reinterpret_cast<const half4_t*>(vbc + vgo + dt * 131072);
    __syncthreads();

    // Per tile t: [stage K(t+1)->NXT] [QK(t) from CUR] [defer-check] [PV(t-1) from VOTH]
    //             [load V(t+1)->VOTH] [softmax-finish pa(t)] [barrier]
#define TILE(T0, CUR, NXT, VOTH, PF, DOPREV) do {                                      \
    if (PF) {                                                                          \
        const char* ks = kbc + (size_t)((T0) + 64) * 256;                              \
        gload16(ks + koff[0], smem + (NXT) + kdst[0]);                                 \
        gload16(ks + koff[1], smem + (NXT) + kdst[1]);                                 \
    }                                                                                  \
    floatx4 sA = {0.f,0.f,0.f,0.f}, sB = {0.f,0.f,0.f,0.f};                            \
    __builtin_amdgcn_s_setprio(1);                                                     \
    _Pragma("unroll")                                                                  \
    for (int dc = 0; dc < 4; ++dc) {                                                   \
        half8_t kf8 = *reinterpret_cast<const half8_t*>(smem + (CUR) + kro[dc]);       \
        sA = __builtin_amdgcn_mfma_f32_16x16x32_f16(kf8, qfA[dc], sA, 0, 0, 0);        \
        sB = __builtin_amdgcn_mfma_f32_16x16x32_f16(kf8, qfB[dc], sB, 0, 0, 0);        \
    }                                                                                  \
    __builtin_amdgcn_s_setprio(0);                                                     \
    float mpA = fmaxf(fmaxf(sA[0], sA[1]), fmaxf(sA[2], sA[3]));                       \
    float mpB = fmaxf(fmaxf(sB[0], sB[1]), fmaxf(sB[2], sB[3]));                       \
    bool ok = (mpA <= mA + 4.0f) && (mpB <= mB + 4.0f);                                \
    if (!__all(ok)) {                                                                  \
        float ra = mpA, rb = mpB;                                                      \
        ra = fmaxf(ra, __shfl_xor(ra, 16)); ra = fmaxf(ra, __shfl_xor(ra, 32));        \
        rb = fmaxf(rb, __shfl_xor(rb, 16)); rb = fmaxf(rb, __shfl_xor(rb, 32));        \
        float nA = fmaxf(mA, ra), nB = fmaxf(mB, rb);                                  \
        float aA = exp2_raw(mA - nA), aB = exp2_raw(mB - nB);                          \
        lA *= aA; lB *= aB;                                                            \
        _Pragma("unroll")                                                              \
        for (int dt = 0; dt < 8; ++dt) { accA[dt] *= aA; accB[dt] *= aB; }             \
        mA = nA; mB = nB;                                                              \
    }                                                                                  \
    if (DOPREV) {                                                                      \
        __builtin_amdgcn_s_setprio(1);                                                 \
        _Pragma("unroll")                                                              \
        for (int dt = 0; dt < 8; ++dt) {                                               \
            accA[dt] = __builtin_amdgcn_mfma_f32_16x16x16f16(VOTH[dt], paA, accA[dt], 0, 0, 0); \
            accB[dt] = __builtin_amdgcn_mfma_f32_16x16x16f16(VOTH[dt], paB, accB[dt], 0, 0, 0); \
        }                                                                              \
        __builtin_amdgcn_s_setprio(0);                                                 \
    }                                                                                  \
    if (PF) {                                                                          \
        const char* vs = vbc + (size_t)((T0) + 64) * 2 + vgo;                          \
        _Pragma("unroll")                                                              \
        for (int dt = 0; dt < 8; ++dt)                                                 \
            VOTH[dt] = *reinterpret_cast<const half4_t*>(vs + dt * 131072);            \
    }                                                                                  \
    {                                                                                  \
        float p0 = exp2_raw(sA[0] - mA), p1 = exp2_raw(sA[1] - mA);                    \
        float p2 = exp2_raw(sA[2] - mA), p3 = exp2_raw(sA[3] - mA);                    \
        lA += (p0 + p1) + (p2 + p3);                                                   \
        half2_t h0 = __builtin_bit_cast(half2_t, __builtin_amdgcn_cvt_pkrtz(p0, p1));  \
        half2_t h1 = __builtin_bit_cast(half2_t, __builtin_amdgcn_cvt_pkrtz(p2, p3));  \
        paA[0] = h0[0]; paA[1] = h0[1]; paA[2] = h1[0]; paA[3] = h1[1];                \
        p0 = exp2_raw(sB[0] - mB); p1 = exp2_raw(sB[1] - mB);                          \
        p2 = exp2_raw(sB[2] - mB); p3 = exp2_raw(sB[3] - mB);                          \
        lB += (p0 + p1) + (p2 + p3);                                                   \
        h0 = __builtin_bit_cast(half2_t, __builtin_amdgcn_cvt_pkrtz(p0, p1));          \
        h1 = __builtin_bit_cast(half2_t, __builtin_amdgcn_cvt_pkrtz(p2, p3));          \
        paB[0] = h0[0]; paB[1] = h0[1]; paB[2] = h1[0]; paB[3] = h1[1];                \
    }                                                                                  \
    __syncthreads();                                                                   \
} while (0)

    // 64 tiles of 64 kv. K buffers alternate 0/16384 by tile parity; V sets v0/v1:
    // tile t consumes V(t-1) from set (t-1)&1 and loads V(t+1) into the same set.
    TILE(0, 0, 16384, v1, 1, 0);
    for (int tt = 64; tt < 3968; tt += 128) {
        TILE(tt,      16384, 0,     v0, 1, 1);
        TILE(tt + 64, 0,     16384, v1, 1, 1);
    }
    TILE(4032, 16384, 0, v0, 0, 1);
#undef TILE

    // epilogue: PV of tile 63 (V(4032) lives in v1, pa = P(4032))
#pragma unroll
    for (int dt = 0; dt < 8; ++dt) {
        accA[dt] = __builtin_amdgcn_mfma_f32_16x16x16f16(v1[dt], paA, accA[dt], 0, 0, 0);
        accB[dt] = __builtin_amdgcn_mfma_f32_16x16x16f16(v1[dt], paB, accB[dt], 0, 0, 0);
    }

    // reduce lane-partial l across hi-groups (once)
    lA += __shfl_xor(lA, 16); lA += __shfl_xor(lA, 32);
    lB += __shfl_xor(lB, 16); lB += __shfl_xor(lB, 32);

    // ---- merge 4 kv-splits ----
    float* red_m = reinterpret_cast<float*>(smem + 34816);   // [4][64]
    float* red_l = reinterpret_cast<float*>(smem + 35840);   // [4][64]
    const int rowA = qg * 32 + lo, rowB = qg * 32 + 16 + lo;
    if (hi == 0) {
        red_m[ksp * 64 + rowA] = mA; red_l[ksp * 64 + rowA] = lA;
        red_m[ksp * 64 + rowB] = mB; red_l[ksp * 64 + rowB] = lB;
    }
    __syncthreads();
    float facA, facB;
    {
        float M = -1e30f, L = 0.f;
#pragma unroll
        for (int s = 0; s < 4; ++s) M = fmaxf(M, red_m[s * 64 + rowA]);
#pragma unroll
        for (int s = 0; s < 4; ++s) L += red_l[s * 64 + rowA] * exp2_raw(red_m[s * 64 + rowA] - M);
        facA = exp2_raw(mA - M) / L;
        M = -1e30f; L = 0.f;
#pragma unroll
        for (int s = 0; s < 4; ++s) M = fmaxf(M, red_m[s * 64 + rowB]);
#pragma unroll
        for (int s = 0; s < 4; ++s) L += red_l[s * 64 + rowB] * exp2_raw(red_m[s * 64 + rowB] - M);
        facB = exp2_raw(mB - M) / L;
    }
    float* out_lds = reinterpret_cast<float*>(smem);  // [64][132] fp32 = 33792B
    for (int s = 0; s < 4; ++s) {
        if (ksp == s) {
#pragma unroll
            for (int dt = 0; dt < 8; ++dt)
#pragma unroll
                for (int r = 0; r < 4; ++r) {
                    int d = dt * 16 + hi * 4 + r;
                    float vA = accA[dt][r] * facA;
                    float vB = accB[dt][r] * facB;
                    float* pA = &out_lds[rowA * 132 + d];
                    float* pB = &out_lds[rowB * 132 + d];
                    if (s == 0) { *pA = vA; *pB = vB; }
                    else        { *pA += vA; *pB += vB; }
                }
        }
        __syncthreads();
    }
    {
        int row = tid >> 3, d0 = (tid & 7) * 16;
        float* op = out + ((size_t)b * T_SEQ + q0 + row) * 128 + d0;
#pragma unroll
        for (int j = 0; j < 4; ++j) {
            float4 v;
            v.x = out_lds[row * 132 + d0 + j * 4 + 0];
            v.y = out_lds[row * 132 + d0 + j * 4 + 1];
            v.z = out_lds[row * 132 + d0 + j * 4 + 2];
            v.w = out_lds[row * 132 + d0 + j * 4 + 3];
            *reinterpret_cast<float4*>(op + j * 4) = v;
        }
    }
}

extern "C" void kernel_launch(void* const* d_in, const int* in_sizes, int n_in,
                              void* d_out, int out_size, void* d_ws, size_t ws_size,
                              hipStream_t stream)
{
    (void)in_sizes; (void)n_in; (void)out_size; (void)ws_size;
    const float* x  = (const float*)d_in[0];
    const float* Wq = (const float*)d_in[1];
    const float* bq = (const float*)d_in[2];
    const float* Wk = (const float*)d_in[3];
    const float* bk = (const float*)d_in[4];
    const float* Wv = (const float*)d_in[5];
    const float* bv = (const float*)d_in[6];
    float* out = (float*)d_out;

    _Float16* qf = (_Float16*)d_ws;
    _Float16* kf = qf + (size_t)4 * T_SEQ * D_HEAD;
    _Float16* vt = kf + (size_t)4 * T_SEQ * D_HEAD;

    proj_kernel<<<dim3(256, 3), 256, 0, stream>>>(x, Wq, bq, Wk, bk, Wv, bv, qf, kf, vt);
    attn_kernel<<<dim3(256), 512, 0, stream>>>(qf, kf, vt, out);
}